// Round 13
// baseline (672.004 us; speedup 1.0000x reference)
//
#include <hip/hip_runtime.h>

// Side Window Filter — bit-exact vs harness np ref (absmax 0.0 contract).
// Math contract (DO NOT REORDER): per output, each of the 8 windows is a
// sequential __builtin_fmaf chain over its taps in row-major (i,j) order,
// fp32 accumulator starting at 0, weights fp32(1/15), fp32(1/9); replicate
// boundary; 8 iterations; fp32 iterates; fp32 d/argmin(first-idx)/update;
// final clip(|x0-res|,0,255).
//
// R23 = R19 byte-identical body, ONE variable changed:
// amdgpu_waves_per_eu(3,3) -> (4,4).
// Rationale (allocator model, 8 data points): the allocator picks VGPR
// counts at occupancy breakpoints (64/84/92 regs ~ 8/6/5 waves) and
// spills to reach them; waves_per_eu acts as a runtime clamp. R19 paid
// twice: spill to an 84-reg/6-wave allocation, then clamped to 3 waves.
// With min=4 the spill-floor budget is 512/4=128 >= the ~102-float live
// set, so the natural settling point is 4 waves / <=128 regs / ZERO
// spill, and the runtime clamp rises 3->4 waves/EU (+33% TLP) — which
// the latency arithmetic says is what R19 lacked (~3000 cyc/pair
// exposed L2/HBM latency vs 5000 cyc peer-wave compute at 3 waves).
// R18's (4,4) failure was confounded by packed v2f even-pair alignment;
// scalar code lacks that pressure.
// Success signature: VGPR 96-128 AND WRITE ~= 49.2 MB.
// Failure A: VGPR 64-84 + WRITE > 80 MB -> allocator structural, R19 is
// the practical floor. Failure B: clean but flat -> R19 ~= floor.
//
// Kept from the ladder: pair rows (15 float4 / 8 outputs), XCD-contiguous
// y-banding (FETCH 103->56 MB, R17/R19), halo-identity edge path
// (absmax 0.0 in R16/R18/R20).

static constexpr int H      = 2048;
static constexpr int W      = 2048;
static constexpr int C      = 3;
static constexpr int WC     = W * C;       // 6144 floats per row
static constexpr int NBX    = 6;           // x-blocks (256 thr x 4 cols)
static constexpr int NPAIRS = H / 2;       // 1024 row-pairs
static constexpr int BAND   = NPAIRS / 8;  // 128 y-pairs per XCD band

// One window-row phase of the 8 directional chains for one output column.
// ph is compile-time at every call site (unrolled loops) so branches fold.
// Chain statement order is IDENTICAL to the verified R10/R15/R19 kernels.
__device__ __forceinline__ void apply_phase_t(float* __restrict__ a,
                                              float t0, float t1, float t2,
                                              float t3, float t4,
                                              int ph, float& center,
                                              float w15, float w9) {
  if (ph == 2) center = t2;
  // L: cols 0..2, all rows
  a[0]=__builtin_fmaf(w15,t0,a[0]); a[0]=__builtin_fmaf(w15,t1,a[0]); a[0]=__builtin_fmaf(w15,t2,a[0]);
  // R: cols 2..4, all rows
  a[1]=__builtin_fmaf(w15,t2,a[1]); a[1]=__builtin_fmaf(w15,t3,a[1]); a[1]=__builtin_fmaf(w15,t4,a[1]);
  if (ph <= 2) {  // U: rows 0..2, all cols
    a[2]=__builtin_fmaf(w15,t0,a[2]); a[2]=__builtin_fmaf(w15,t1,a[2]); a[2]=__builtin_fmaf(w15,t2,a[2]);
    a[2]=__builtin_fmaf(w15,t3,a[2]); a[2]=__builtin_fmaf(w15,t4,a[2]);
    // NW / NE
    a[4]=__builtin_fmaf(w9,t0,a[4]); a[4]=__builtin_fmaf(w9,t1,a[4]); a[4]=__builtin_fmaf(w9,t2,a[4]);
    a[5]=__builtin_fmaf(w9,t2,a[5]); a[5]=__builtin_fmaf(w9,t3,a[5]); a[5]=__builtin_fmaf(w9,t4,a[5]);
  }
  if (ph >= 2) {  // D: rows 2..4, all cols
    a[3]=__builtin_fmaf(w15,t0,a[3]); a[3]=__builtin_fmaf(w15,t1,a[3]); a[3]=__builtin_fmaf(w15,t2,a[3]);
    a[3]=__builtin_fmaf(w15,t3,a[3]); a[3]=__builtin_fmaf(w15,t4,a[3]);
    // SW / SE
    a[6]=__builtin_fmaf(w9,t0,a[6]); a[6]=__builtin_fmaf(w9,t1,a[6]); a[6]=__builtin_fmaf(w9,t2,a[6]);
    a[7]=__builtin_fmaf(w9,t2,a[7]); a[7]=__builtin_fmaf(w9,t3,a[7]); a[7]=__builtin_fmaf(w9,t4,a[7]);
  }
}

// fp32 d/argmin/update epilogue for one output column (order-contractual).
__device__ __forceinline__ float finish(const float* __restrict__ a,
                                        float center) {
  float best  = a[0] - center;
  float besta = fabsf(best);
#pragma unroll
  for (int m = 1; m < 8; ++m) {
    const float d  = a[m] - center;
    const float ab = fabsf(d);
    if (ab < besta) { besta = ab; best = d; }
  }
  return center + best;
}

template<bool FINAL>
__global__ __attribute__((amdgpu_waves_per_eu(4, 4))) __launch_bounds__(256)
void swf_pg(const float* __restrict__ src, float* __restrict__ dst,
            const float* __restrict__ x0) {
  // R17/R19-proven XCD-contiguous y-banding: flat%8 ~ XCD id -> contiguous
  // 128-pair band; everything downstream identical to R15/R19.
  const int flat  = blockIdx.y * NBX + blockIdx.x;
  const int xcd   = flat & 7;
  const int idx   = flat >> 3;
  const int yb    = idx / NBX;
  const int xb    = idx - yb * NBX;
  const int ypair = xcd * BAND + yb;
  const int col4  = (xb * 256 + threadIdx.x) * 4;   // 16B-aligned
  const int yA    = ypair * 2;                      // rows yA, yA+1

  const float w15 = 1.0f / 15.0f;   // fp32(1/15)
  const float w9  = 1.0f / 9.0f;    // fp32(1/9)

  float accA[4][8], accB[4][8];
#pragma unroll
  for (int k = 0; k < 4; ++k)
#pragma unroll
    for (int m = 0; m < 8; ++m) { accA[k][m] = 0.0f; accB[k][m] = 0.0f; }
  float centerA[4], centerB[4];

  // fast iff all taps for cols col4..col4+3 lie in [col4-8, col4+12)
  const bool fastc = (col4 >= 8) && (col4 <= WC - 12);
  if (fastc) {
    const float* colbase = src + (col4 - 8);
    // walk the 6-row union: row yA+i-2 feeds phase i of A (i<=4) and
    // phase i-1 of B (i>=1)
#pragma unroll
    for (int i = 0; i < 6; ++i) {
      int hy = yA + i - 2;
      hy = hy < 0 ? 0 : (hy > H - 1 ? H - 1 : hy);     // replicate rows
      const float4* rp = (const float4*)(colbase + (size_t)hy * WC);
      const float4 q0 = rp[0], q1 = rp[1], q2 = rp[2], q3 = rp[3], q4 = rp[4];
      const float r[20] = {q0.x,q0.y,q0.z,q0.w, q1.x,q1.y,q1.z,q1.w,
                           q2.x,q2.y,q2.z,q2.w, q3.x,q3.y,q3.z,q3.w,
                           q4.x,q4.y,q4.z,q4.w};
#pragma unroll
      for (int k = 0; k < 4; ++k) {
        // tap j of output col4+k -> r[k + 3j + 2]
        const float t0 = r[k+2], t1 = r[k+5], t2 = r[k+8],
                    t3 = r[k+11], t4 = r[k+14];
        if (i <= 4) apply_phase_t(accA[k], t0,t1,t2,t3,t4, i,     centerA[k], w15, w9);
        if (i >= 1) apply_phase_t(accB[k], t0,t1,t2,t3,t4, i - 1, centerB[k], w15, w9);
      }
    }
  } else {
    // edge columns (col4 in {0,4,WC-8,WC-4}): scalar clamped gather,
    // identical chain structure; column clamps hoisted (row-invariant)
    int cjk[4][5];
#pragma unroll
    for (int k = 0; k < 4; ++k) {
      const int col = col4 + k;
      const int w   = col / 3;
      const int c   = col - w * 3;
#pragma unroll
      for (int j = 0; j < 5; ++j) {
        int wj = w + j - 2;
        wj = wj < 0 ? 0 : (wj > W - 1 ? W - 1 : wj);   // replicate cols
        cjk[k][j] = wj * 3 + c;
      }
    }
#pragma unroll
    for (int i = 0; i < 6; ++i) {
      int hy = yA + i - 2;
      hy = hy < 0 ? 0 : (hy > H - 1 ? H - 1 : hy);
      const float* rr = src + (size_t)hy * WC;
#pragma unroll
      for (int k = 0; k < 4; ++k) {
        const float t0 = rr[cjk[k][0]], t1 = rr[cjk[k][1]], t2 = rr[cjk[k][2]],
                    t3 = rr[cjk[k][3]], t4 = rr[cjk[k][4]];
        if (i <= 4) apply_phase_t(accA[k], t0,t1,t2,t3,t4, i,     centerA[k], w15, w9);
        if (i >= 1) apply_phase_t(accB[k], t0,t1,t2,t3,t4, i - 1, centerB[k], w15, w9);
      }
    }
  }

  // epilogue: two output rows, fp32 d/argmin/update, float4 stores
#pragma unroll
  for (int half = 0; half < 2; ++half) {
    const int y = yA + half;
    float4 xv4;
    if (FINAL) xv4 = *(const float4*)(x0 + (size_t)y * WC + col4);
    float o[4];
#pragma unroll
    for (int k = 0; k < 4; ++k) {
      const float res = half ? finish(accB[k], centerB[k])
                             : finish(accA[k], centerA[k]);
      if (FINAL) {
        const float xv = (k == 0) ? xv4.x : (k == 1) ? xv4.y
                       : (k == 2) ? xv4.z : xv4.w;
        float diff = fabsf(xv - res);
        o[k] = diff > 255.0f ? 255.0f : diff;
      } else {
        o[k] = res;
      }
    }
    float4 ov;
    ov.x = o[0]; ov.y = o[1]; ov.z = o[2]; ov.w = o[3];
    *(float4*)(dst + (size_t)y * WC + col4) = ov;
  }
}

extern "C" void kernel_launch(void* const* d_in, const int* in_sizes, int n_in,
                              void* d_out, int out_size, void* d_ws, size_t ws_size,
                              hipStream_t stream) {
  const float* x0  = (const float*)d_in[0];
  float*       out = (float*)d_out;
  float*       ws  = (float*)d_ws;   // needs H*W*C*4 = 50.3 MB

  dim3 grid(NBX, NPAIRS);            // 6 x-blocks, 1024 row-pairs
  dim3 block(256);

  swf_pg<false><<<grid, block, 0, stream>>>(x0,  ws,  nullptr);  // iter 1
  swf_pg<false><<<grid, block, 0, stream>>>(ws,  out, nullptr);  // iter 2
  swf_pg<false><<<grid, block, 0, stream>>>(out, ws,  nullptr);  // iter 3
  swf_pg<false><<<grid, block, 0, stream>>>(ws,  out, nullptr);  // iter 4
  swf_pg<false><<<grid, block, 0, stream>>>(out, ws,  nullptr);  // iter 5
  swf_pg<false><<<grid, block, 0, stream>>>(ws,  out, nullptr);  // iter 6
  swf_pg<false><<<grid, block, 0, stream>>>(out, ws,  nullptr);  // iter 7
  swf_pg<true ><<<grid, block, 0, stream>>>(ws,  out, x0);       // iter 8 + diff
}

// Round 14
// 452.239 us; speedup vs baseline: 1.4859x; 1.4859x over previous
//
#include <hip/hip_runtime.h>

// Side Window Filter — bit-exact vs harness np ref (absmax 0.0 contract).
// Math contract (DO NOT REORDER): per output, each of the 8 windows is a
// sequential __builtin_fmaf chain over its taps in row-major (i,j) order,
// fp32 accumulator starting at 0, weights fp32(1/15), fp32(1/9); replicate
// boundary; 8 iterations; fp32 iterates; fp32 d/argmin(first-idx)/update;
// final clip(|x0-res|,0,255).
//
// R24 = R19 BYTE-IDENTICAL RESTORE (session best: 454.3 us total).
// R23's (4,4) experiment fired pre-committed Failure A (VGPR 64, 497 MB
// write = ~38 floats/thread spilled): the allocator ignores waves_per_eu
// budgets and settles on occupancy breakpoints; (3,3)+launch_bounds(256)
// is the empirically unique combo yielding the good 84-reg allocation.
// Session-proven wins embodied here:
//   - pair-processing: rows (2y,2y+1) share 4/6 window rows; one 6-row
//     union walk = 15 float4 loads / 8 outputs (vs 25 naive).
//   - XCD-contiguous y-banding: flat%8 selects a contiguous 128-pair
//     band -> FETCH 103->56 MB (R17/R19 measured).
//   - halo-identity edge path (absmax 0.0 verified in R16/R18/R20).
// Practical floor statement: VALU ~25-31us, L1 ~19us, HBM ~18us per
// dispatch vs 57us wall at 3 waves/EU — residual is exposed latency the
// allocator-capped occupancy cannot hide; all structural alternatives
// (LDS x3, prefetch x2, packed x2, grid-condense, occupancy knobs x5)
// regressed or were neutral across R11-R23.

static constexpr int H      = 2048;
static constexpr int W      = 2048;
static constexpr int C      = 3;
static constexpr int WC     = W * C;       // 6144 floats per row
static constexpr int NBX    = 6;           // x-blocks (256 thr x 4 cols)
static constexpr int NPAIRS = H / 2;       // 1024 row-pairs
static constexpr int BAND   = NPAIRS / 8;  // 128 y-pairs per XCD band

// One window-row phase of the 8 directional chains for one output column.
// ph is compile-time at every call site (unrolled loops) so branches fold.
// Chain statement order is IDENTICAL to the verified R10/R15 kernels.
__device__ __forceinline__ void apply_phase_t(float* __restrict__ a,
                                              float t0, float t1, float t2,
                                              float t3, float t4,
                                              int ph, float& center,
                                              float w15, float w9) {
  if (ph == 2) center = t2;
  // L: cols 0..2, all rows
  a[0]=__builtin_fmaf(w15,t0,a[0]); a[0]=__builtin_fmaf(w15,t1,a[0]); a[0]=__builtin_fmaf(w15,t2,a[0]);
  // R: cols 2..4, all rows
  a[1]=__builtin_fmaf(w15,t2,a[1]); a[1]=__builtin_fmaf(w15,t3,a[1]); a[1]=__builtin_fmaf(w15,t4,a[1]);
  if (ph <= 2) {  // U: rows 0..2, all cols
    a[2]=__builtin_fmaf(w15,t0,a[2]); a[2]=__builtin_fmaf(w15,t1,a[2]); a[2]=__builtin_fmaf(w15,t2,a[2]);
    a[2]=__builtin_fmaf(w15,t3,a[2]); a[2]=__builtin_fmaf(w15,t4,a[2]);
    // NW / NE
    a[4]=__builtin_fmaf(w9,t0,a[4]); a[4]=__builtin_fmaf(w9,t1,a[4]); a[4]=__builtin_fmaf(w9,t2,a[4]);
    a[5]=__builtin_fmaf(w9,t2,a[5]); a[5]=__builtin_fmaf(w9,t3,a[5]); a[5]=__builtin_fmaf(w9,t4,a[5]);
  }
  if (ph >= 2) {  // D: rows 2..4, all cols
    a[3]=__builtin_fmaf(w15,t0,a[3]); a[3]=__builtin_fmaf(w15,t1,a[3]); a[3]=__builtin_fmaf(w15,t2,a[3]);
    a[3]=__builtin_fmaf(w15,t3,a[3]); a[3]=__builtin_fmaf(w15,t4,a[3]);
    // SW / SE
    a[6]=__builtin_fmaf(w9,t0,a[6]); a[6]=__builtin_fmaf(w9,t1,a[6]); a[6]=__builtin_fmaf(w9,t2,a[6]);
    a[7]=__builtin_fmaf(w9,t2,a[7]); a[7]=__builtin_fmaf(w9,t3,a[7]); a[7]=__builtin_fmaf(w9,t4,a[7]);
  }
}

// fp32 d/argmin/update epilogue for one output column (order-contractual).
__device__ __forceinline__ float finish(const float* __restrict__ a,
                                        float center) {
  float best  = a[0] - center;
  float besta = fabsf(best);
#pragma unroll
  for (int m = 1; m < 8; ++m) {
    const float d  = a[m] - center;
    const float ab = fabsf(d);
    if (ab < besta) { besta = ab; best = d; }
  }
  return center + best;
}

template<bool FINAL>
__global__ __attribute__((amdgpu_waves_per_eu(3, 3))) __launch_bounds__(256)
void swf_pg(const float* __restrict__ src, float* __restrict__ dst,
            const float* __restrict__ x0) {
  // R17-proven XCD-contiguous y-banding: flat%8 ~ XCD id -> contiguous
  // 128-pair band; everything downstream identical to R15.
  const int flat  = blockIdx.y * NBX + blockIdx.x;
  const int xcd   = flat & 7;
  const int idx   = flat >> 3;
  const int yb    = idx / NBX;
  const int xb    = idx - yb * NBX;
  const int ypair = xcd * BAND + yb;
  const int col4  = (xb * 256 + threadIdx.x) * 4;   // 16B-aligned
  const int yA    = ypair * 2;                      // rows yA, yA+1

  const float w15 = 1.0f / 15.0f;   // fp32(1/15)
  const float w9  = 1.0f / 9.0f;    // fp32(1/9)

  float accA[4][8], accB[4][8];
#pragma unroll
  for (int k = 0; k < 4; ++k)
#pragma unroll
    for (int m = 0; m < 8; ++m) { accA[k][m] = 0.0f; accB[k][m] = 0.0f; }
  float centerA[4], centerB[4];

  // fast iff all taps for cols col4..col4+3 lie in [col4-8, col4+12)
  const bool fastc = (col4 >= 8) && (col4 <= WC - 12);
  if (fastc) {
    const float* colbase = src + (col4 - 8);
    // walk the 6-row union: row yA+i-2 feeds phase i of A (i<=4) and
    // phase i-1 of B (i>=1)
#pragma unroll
    for (int i = 0; i < 6; ++i) {
      int hy = yA + i - 2;
      hy = hy < 0 ? 0 : (hy > H - 1 ? H - 1 : hy);     // replicate rows
      const float4* rp = (const float4*)(colbase + (size_t)hy * WC);
      const float4 q0 = rp[0], q1 = rp[1], q2 = rp[2], q3 = rp[3], q4 = rp[4];
      const float r[20] = {q0.x,q0.y,q0.z,q0.w, q1.x,q1.y,q1.z,q1.w,
                           q2.x,q2.y,q2.z,q2.w, q3.x,q3.y,q3.z,q3.w,
                           q4.x,q4.y,q4.z,q4.w};
#pragma unroll
      for (int k = 0; k < 4; ++k) {
        // tap j of output col4+k -> r[k + 3j + 2]
        const float t0 = r[k+2], t1 = r[k+5], t2 = r[k+8],
                    t3 = r[k+11], t4 = r[k+14];
        if (i <= 4) apply_phase_t(accA[k], t0,t1,t2,t3,t4, i,     centerA[k], w15, w9);
        if (i >= 1) apply_phase_t(accB[k], t0,t1,t2,t3,t4, i - 1, centerB[k], w15, w9);
      }
    }
  } else {
    // edge columns (col4 in {0,4,WC-8,WC-4}): scalar clamped gather,
    // identical chain structure; column clamps hoisted (row-invariant)
    int cjk[4][5];
#pragma unroll
    for (int k = 0; k < 4; ++k) {
      const int col = col4 + k;
      const int w   = col / 3;
      const int c   = col - w * 3;
#pragma unroll
      for (int j = 0; j < 5; ++j) {
        int wj = w + j - 2;
        wj = wj < 0 ? 0 : (wj > W - 1 ? W - 1 : wj);   // replicate cols
        cjk[k][j] = wj * 3 + c;
      }
    }
#pragma unroll
    for (int i = 0; i < 6; ++i) {
      int hy = yA + i - 2;
      hy = hy < 0 ? 0 : (hy > H - 1 ? H - 1 : hy);
      const float* rr = src + (size_t)hy * WC;
#pragma unroll
      for (int k = 0; k < 4; ++k) {
        const float t0 = rr[cjk[k][0]], t1 = rr[cjk[k][1]], t2 = rr[cjk[k][2]],
                    t3 = rr[cjk[k][3]], t4 = rr[cjk[k][4]];
        if (i <= 4) apply_phase_t(accA[k], t0,t1,t2,t3,t4, i,     centerA[k], w15, w9);
        if (i >= 1) apply_phase_t(accB[k], t0,t1,t2,t3,t4, i - 1, centerB[k], w15, w9);
      }
    }
  }

  // epilogue: two output rows, fp32 d/argmin/update, float4 stores
#pragma unroll
  for (int half = 0; half < 2; ++half) {
    const int y = yA + half;
    float4 xv4;
    if (FINAL) xv4 = *(const float4*)(x0 + (size_t)y * WC + col4);
    float o[4];
#pragma unroll
    for (int k = 0; k < 4; ++k) {
      const float res = half ? finish(accB[k], centerB[k])
                             : finish(accA[k], centerA[k]);
      if (FINAL) {
        const float xv = (k == 0) ? xv4.x : (k == 1) ? xv4.y
                       : (k == 2) ? xv4.z : xv4.w;
        float diff = fabsf(xv - res);
        o[k] = diff > 255.0f ? 255.0f : diff;
      } else {
        o[k] = res;
      }
    }
    float4 ov;
    ov.x = o[0]; ov.y = o[1]; ov.z = o[2]; ov.w = o[3];
    *(float4*)(dst + (size_t)y * WC + col4) = ov;
  }
}

extern "C" void kernel_launch(void* const* d_in, const int* in_sizes, int n_in,
                              void* d_out, int out_size, void* d_ws, size_t ws_size,
                              hipStream_t stream) {
  const float* x0  = (const float*)d_in[0];
  float*       out = (float*)d_out;
  float*       ws  = (float*)d_ws;   // needs H*W*C*4 = 50.3 MB

  dim3 grid(NBX, NPAIRS);            // 6 x-blocks, 1024 row-pairs
  dim3 block(256);

  swf_pg<false><<<grid, block, 0, stream>>>(x0,  ws,  nullptr);  // iter 1
  swf_pg<false><<<grid, block, 0, stream>>>(ws,  out, nullptr);  // iter 2
  swf_pg<false><<<grid, block, 0, stream>>>(out, ws,  nullptr);  // iter 3
  swf_pg<false><<<grid, block, 0, stream>>>(ws,  out, nullptr);  // iter 4
  swf_pg<false><<<grid, block, 0, stream>>>(out, ws,  nullptr);  // iter 5
  swf_pg<false><<<grid, block, 0, stream>>>(ws,  out, nullptr);  // iter 6
  swf_pg<false><<<grid, block, 0, stream>>>(out, ws,  nullptr);  // iter 7
  swf_pg<true ><<<grid, block, 0, stream>>>(ws,  out, x0);       // iter 8 + diff
}